// Round 1
// baseline (1061.059 us; speedup 1.0000x reference)
//
#include <hip/hip_runtime.h>
#include <math.h>

// Problem constants
#define BATCH   8
#define QLEN    256
#define KLEN    2048
#define KDIM    512
#define ADIMC   512
#define NHEADS  4
#define DKH     128     // ADIM / NHEADS
#define CHUNKW  4

static constexpr float INV_SCALE = 0.04419417382415922f; // 1/sqrt(512)
static constexpr float EPSV = 1e-6f;

// ---------------------------------------------------------------------------
// Projection GEMM: C[M,N] = A[M,K] @ W[K,N] + bias[N]
// BM=BN=64, BK=16, 256 threads, 4x4 per thread.
// ---------------------------------------------------------------------------
__global__ __launch_bounds__(256) void proj_gemm(
    const float* __restrict__ A, const float* __restrict__ W,
    const float* __restrict__ bias, float* __restrict__ C,
    int M, int K, int N)
{
    __shared__ float As[16][65];
    __shared__ float Ws[16][65];
    const int tid = threadIdx.x;
    const int bm = blockIdx.y * 64, bn = blockIdx.x * 64;
    const int lr = tid >> 2, lc = (tid & 3) * 4;      // A-tile load: row, k-col
    const int wr = tid >> 4, wc = (tid & 15) * 4;     // W-tile load: k-row, n-col
    const int tm = (tid >> 4) * 4, tn = (tid & 15) * 4;
    float acc[4][4] = {};

    for (int k0 = 0; k0 < K; k0 += 16) {
        float4 av = *(const float4*)(A + (size_t)(bm + lr) * K + k0 + lc);
        float4 wv = *(const float4*)(W + (size_t)(k0 + wr) * N + bn + wc);
        As[lc + 0][lr] = av.x; As[lc + 1][lr] = av.y;
        As[lc + 2][lr] = av.z; As[lc + 3][lr] = av.w;
        Ws[wr][wc + 0] = wv.x; Ws[wr][wc + 1] = wv.y;
        Ws[wr][wc + 2] = wv.z; Ws[wr][wc + 3] = wv.w;
        __syncthreads();
        #pragma unroll
        for (int kk = 0; kk < 16; ++kk) {
            float a0 = As[kk][tm + 0], a1 = As[kk][tm + 1];
            float a2 = As[kk][tm + 2], a3 = As[kk][tm + 3];
            float b0 = Ws[kk][tn + 0], b1 = Ws[kk][tn + 1];
            float b2 = Ws[kk][tn + 2], b3 = Ws[kk][tn + 3];
            acc[0][0] += a0 * b0; acc[0][1] += a0 * b1; acc[0][2] += a0 * b2; acc[0][3] += a0 * b3;
            acc[1][0] += a1 * b0; acc[1][1] += a1 * b1; acc[1][2] += a1 * b2; acc[1][3] += a1 * b3;
            acc[2][0] += a2 * b0; acc[2][1] += a2 * b1; acc[2][2] += a2 * b2; acc[2][3] += a2 * b3;
            acc[3][0] += a3 * b0; acc[3][1] += a3 * b1; acc[3][2] += a3 * b2; acc[3][3] += a3 * b3;
        }
        __syncthreads();
    }
    const float c0 = bias[bn + tn + 0], c1 = bias[bn + tn + 1];
    const float c2 = bias[bn + tn + 2], c3 = bias[bn + tn + 3];
    #pragma unroll
    for (int i = 0; i < 4; ++i) {
        float4 o;
        o.x = acc[i][0] + c0; o.y = acc[i][1] + c1;
        o.z = acc[i][2] + c2; o.w = acc[i][3] + c3;
        *(float4*)(C + (size_t)(bm + tm + i) * N + bn + tn) = o;
    }
}

// ---------------------------------------------------------------------------
// Batched NT GEMM -> p_choose: per batch b,
//   e[q,k] = (q_m[b,q,:] . k_m[b,k,:]) * INV_SCALE + r
//   p      = sigmoid(e + noise[b,q,k])
// A = q_m[b]   (256 x 512, row-major, K contiguous)
// B = k_m[b]   (2048 x 512, row-major, K contiguous)
// ---------------------------------------------------------------------------
__global__ __launch_bounds__(256) void pchoose_gemm(
    const float* __restrict__ qm, const float* __restrict__ km,
    const float* __restrict__ noise, const float* __restrict__ rp,
    float* __restrict__ p)
{
    const int b = blockIdx.z;
    const float* A = qm + (size_t)b * QLEN * ADIMC;
    const float* B = km + (size_t)b * KLEN * ADIMC;
    __shared__ float As[16][65];
    __shared__ float Bs[16][65];
    const int tid = threadIdx.x;
    const int bm = blockIdx.y * 64, bn = blockIdx.x * 64;   // bm: q, bn: k
    const int lr = tid >> 2, lc = (tid & 3) * 4;
    const int tm = (tid >> 4) * 4, tn = (tid & 15) * 4;
    float acc[4][4] = {};

    for (int k0 = 0; k0 < ADIMC; k0 += 16) {
        float4 av = *(const float4*)(A + (size_t)(bm + lr) * ADIMC + k0 + lc);
        float4 bv = *(const float4*)(B + (size_t)(bn + lr) * ADIMC + k0 + lc);
        As[lc + 0][lr] = av.x; As[lc + 1][lr] = av.y;
        As[lc + 2][lr] = av.z; As[lc + 3][lr] = av.w;
        Bs[lc + 0][lr] = bv.x; Bs[lc + 1][lr] = bv.y;
        Bs[lc + 2][lr] = bv.z; Bs[lc + 3][lr] = bv.w;
        __syncthreads();
        #pragma unroll
        for (int kk = 0; kk < 16; ++kk) {
            float a0 = As[kk][tm + 0], a1 = As[kk][tm + 1];
            float a2 = As[kk][tm + 2], a3 = As[kk][tm + 3];
            float b0 = Bs[kk][tn + 0], b1 = Bs[kk][tn + 1];
            float b2 = Bs[kk][tn + 2], b3 = Bs[kk][tn + 3];
            acc[0][0] += a0 * b0; acc[0][1] += a0 * b1; acc[0][2] += a0 * b2; acc[0][3] += a0 * b3;
            acc[1][0] += a1 * b0; acc[1][1] += a1 * b1; acc[1][2] += a1 * b2; acc[1][3] += a1 * b3;
            acc[2][0] += a2 * b0; acc[2][1] += a2 * b1; acc[2][2] += a2 * b2; acc[2][3] += a2 * b3;
            acc[3][0] += a3 * b0; acc[3][1] += a3 * b1; acc[3][2] += a3 * b2; acc[3][3] += a3 * b3;
        }
        __syncthreads();
    }
    const float rv = rp[0];
    #pragma unroll
    for (int i = 0; i < 4; ++i) {
        const int q = bm + tm + i;
        const size_t rowoff = ((size_t)b * QLEN + q) * KLEN;
        #pragma unroll
        for (int j = 0; j < 4; ++j) {
            const int k = bn + tn + j;
            float e = acc[i][j] * INV_SCALE + rv + noise[rowoff + k];
            p[rowoff + k] = 1.0f / (1.0f + expf(-e));
        }
    }
}

// ---------------------------------------------------------------------------
// Batched NT GEMM -> e_chunk: per (b,h),
//   e[q,k] = (q_c[b,q,h,:] . k_c[b,k,h,:]) * INV_SCALE   -> out[b,h,q,k]
// q_c/k_c are [.., 512] with head slice at offset h*128, K=128.
// ---------------------------------------------------------------------------
__global__ __launch_bounds__(256) void echunk_gemm(
    const float* __restrict__ qc, const float* __restrict__ kc,
    float* __restrict__ out)
{
    const int z = blockIdx.z;
    const int b = z >> 2, h = z & 3;
    const float* A = qc + (size_t)b * QLEN * ADIMC + h * DKH;
    const float* B = kc + (size_t)b * KLEN * ADIMC + h * DKH;
    __shared__ float As[16][65];
    __shared__ float Bs[16][65];
    const int tid = threadIdx.x;
    const int bm = blockIdx.y * 64, bn = blockIdx.x * 64;
    const int lr = tid >> 2, lc = (tid & 3) * 4;
    const int tm = (tid >> 4) * 4, tn = (tid & 15) * 4;
    float acc[4][4] = {};

    for (int k0 = 0; k0 < DKH; k0 += 16) {
        float4 av = *(const float4*)(A + (size_t)(bm + lr) * ADIMC + k0 + lc);
        float4 bv = *(const float4*)(B + (size_t)(bn + lr) * ADIMC + k0 + lc);
        As[lc + 0][lr] = av.x; As[lc + 1][lr] = av.y;
        As[lc + 2][lr] = av.z; As[lc + 3][lr] = av.w;
        Bs[lc + 0][lr] = bv.x; Bs[lc + 1][lr] = bv.y;
        Bs[lc + 2][lr] = bv.z; Bs[lc + 3][lr] = bv.w;
        __syncthreads();
        #pragma unroll
        for (int kk = 0; kk < 16; ++kk) {
            float a0 = As[kk][tm + 0], a1 = As[kk][tm + 1];
            float a2 = As[kk][tm + 2], a3 = As[kk][tm + 3];
            float b0 = Bs[kk][tn + 0], b1 = Bs[kk][tn + 1];
            float b2 = Bs[kk][tn + 2], b3 = Bs[kk][tn + 3];
            acc[0][0] += a0 * b0; acc[0][1] += a0 * b1; acc[0][2] += a0 * b2; acc[0][3] += a0 * b3;
            acc[1][0] += a1 * b0; acc[1][1] += a1 * b1; acc[1][2] += a1 * b2; acc[1][3] += a1 * b3;
            acc[2][0] += a2 * b0; acc[2][1] += a2 * b1; acc[2][2] += a2 * b2; acc[2][3] += a2 * b3;
            acc[3][0] += a3 * b0; acc[3][1] += a3 * b1; acc[3][2] += a3 * b2; acc[3][3] += a3 * b3;
        }
        __syncthreads();
    }
    #pragma unroll
    for (int i = 0; i < 4; ++i) {
        const int q = bm + tm + i;
        const size_t rowoff = (((size_t)b * NHEADS + h) * QLEN + q) * KLEN;
        float4 o;
        o.x = acc[i][0] * INV_SCALE; o.y = acc[i][1] * INV_SCALE;
        o.z = acc[i][2] * INV_SCALE; o.w = acc[i][3] * INV_SCALE;
        *(float4*)(out + rowoff + bn + tn) = o;
    }
}

// ---------------------------------------------------------------------------
// cumprod_1mp: per (b,q) row of 2048:
//   l[k]  = log(clip(1 - p[k], 1e-6, 1))
//   cp[k] = exp(exclusive_cumsum(l)[k])
// One 256-thread block per row; 8 consecutive elems per thread.
// ---------------------------------------------------------------------------
__global__ __launch_bounds__(256) void cumprod_kernel(
    const float* __restrict__ p, float* __restrict__ cp)
{
    const size_t row = blockIdx.x;
    const float* pr = p + row * KLEN;
    float* cr = cp + row * KLEN;
    const int tid = threadIdx.x;
    const int lane = tid & 63, wid = tid >> 6;
    __shared__ float waveTot[4];

    float4 v0 = *(const float4*)(pr + tid * 8);
    float4 v1 = *(const float4*)(pr + tid * 8 + 4);
    float pv[8] = {v0.x, v0.y, v0.z, v0.w, v1.x, v1.y, v1.z, v1.w};
    float excl[8];
    float run = 0.0f;
    #pragma unroll
    for (int j = 0; j < 8; ++j) {
        float l = logf(fminf(fmaxf(1.0f - pv[j], EPSV), 1.0f));
        excl[j] = run;
        run += l;
    }
    // block-wide exclusive scan of per-thread totals
    float s = run;
    #pragma unroll
    for (int off = 1; off < 64; off <<= 1) {
        float v = __shfl_up(s, off);
        if (lane >= off) s += v;
    }
    if (lane == 63) waveTot[wid] = s;
    __syncthreads();
    float wex = 0.0f;
    for (int w = 0; w < wid; ++w) wex += waveTot[w];
    const float texcl = wex + s - run;

    float4 o0, o1;
    o0.x = expf(texcl + excl[0]); o0.y = expf(texcl + excl[1]);
    o0.z = expf(texcl + excl[2]); o0.w = expf(texcl + excl[3]);
    o1.x = expf(texcl + excl[4]); o1.y = expf(texcl + excl[5]);
    o1.z = expf(texcl + excl[6]); o1.w = expf(texcl + excl[7]);
    *(float4*)(cr + tid * 8) = o0;
    *(float4*)(cr + tid * 8 + 4) = o1;
}

// ---------------------------------------------------------------------------
// alpha recurrence (serial over q): one block per batch, 1024 threads,
// 2 elements per thread. alpha_i = p_i * cp_i * cumsum(aw_prev / clip(cp_i)).
// alpha is written IN PLACE over p (row i of p is dead after step i).
// ---------------------------------------------------------------------------
__global__ __launch_bounds__(1024) void alpha_kernel(
    float* __restrict__ p_alpha, const float* __restrict__ cp)
{
    const int b = blockIdx.x;
    const int tid = threadIdx.x;
    const int lane = tid & 63, wid = tid >> 6;
    __shared__ float waveTot[16];

    float* prow = p_alpha + (size_t)b * QLEN * KLEN;
    const float* crow = cp + (size_t)b * QLEN * KLEN;

    float aw0 = (tid == 0) ? 1.0f : 0.0f;   // one-hot at k=0
    float aw1 = 0.0f;

    float2 pc = *(const float2*)(prow + tid * 2);
    float2 cc = *(const float2*)(crow + tid * 2);

    for (int i = 0; i < QLEN; ++i) {
        float2 pn = {0.0f, 0.0f}, cn = {0.0f, 0.0f};
        if (i < QLEN - 1) {   // prefetch next row to hide latency
            pn = *(const float2*)(prow + (size_t)(i + 1) * KLEN + tid * 2);
            cn = *(const float2*)(crow + (size_t)(i + 1) * KLEN + tid * 2);
        }
        const float c0 = fminf(fmaxf(cc.x, EPSV), 1.0f);
        const float c1 = fminf(fmaxf(cc.y, EPSV), 1.0f);
        const float t0 = aw0 / c0;
        const float t1 = aw1 / c1;
        const float tot = t0 + t1;
        float s = tot;
        #pragma unroll
        for (int off = 1; off < 64; off <<= 1) {
            float v = __shfl_up(s, off);
            if (lane >= off) s += v;
        }
        if (lane == 63) waveTot[wid] = s;
        __syncthreads();
        float wex = 0.0f;
        for (int w = 0; w < wid; ++w) wex += waveTot[w];
        const float excl = wex + s - tot;   // exclusive prefix over thread totals
        const float a0 = pc.x * cc.x * (excl + t0);
        const float a1 = pc.y * cc.y * (excl + t0 + t1);
        float2 ov; ov.x = a0; ov.y = a1;
        *(float2*)(prow + (size_t)i * KLEN + tid * 2) = ov;
        aw0 = a0; aw1 = a1;
        __syncthreads();   // waveTot reused next iteration
        pc = pn; cc = cn;
    }
}

// ---------------------------------------------------------------------------
// beta: per (b,h,q) row of 2048 (e_chunk already in d_out, overwritten):
//   mx    = max_k e[k]
//   se    = max(exp(e - mx), 1e-5)
//   denom = movsum(se, back=3, fwd=0)
//   u     = alpha / denom
//   beta  = se * movsum(u, back=0, fwd=3)
// ---------------------------------------------------------------------------
__global__ __launch_bounds__(256) void beta_kernel(
    float* __restrict__ eo, const float* __restrict__ alpha)
{
    __shared__ float sse[KLEN + 3];   // [0..2]=0 pad, elem k at sse[k+3]
    __shared__ float su[KLEN + 3];    // elem k at su[k], [KLEN..KLEN+2]=0 pad
    __shared__ float wmax[4];

    const int tid = threadIdx.x;
    const int lane = tid & 63, wid = tid >> 6;
    const int row = blockIdx.x;                 // [B*H*Q]
    const int q = row & (QLEN - 1);
    const int b = row >> 10;                    // row / (NHEADS*QLEN)
    float* erow = eo + (size_t)row * KLEN;
    const float* arow = alpha + ((size_t)b * QLEN + q) * KLEN;

    if (tid < 3) { sse[tid] = 0.0f; su[KLEN + tid] = 0.0f; }

    float ev[8];
    float lm = -INFINITY;
    #pragma unroll
    for (int j = 0; j < 8; ++j) {
        const int k = tid + 256 * j;
        ev[j] = erow[k];
        lm = fmaxf(lm, ev[j]);
    }
    #pragma unroll
    for (int off = 32; off > 0; off >>= 1) lm = fmaxf(lm, __shfl_xor(lm, off));
    if (lane == 0) wmax[wid] = lm;
    __syncthreads();
    const float mx = fmaxf(fmaxf(wmax[0], wmax[1]), fmaxf(wmax[2], wmax[3]));

    #pragma unroll
    for (int j = 0; j < 8; ++j) {
        const int k = tid + 256 * j;
        sse[k + 3] = fmaxf(expf(ev[j] - mx), 1e-5f);
    }
    __syncthreads();

    #pragma unroll
    for (int j = 0; j < 8; ++j) {
        const int k = tid + 256 * j;
        const float denom = sse[k + 3] + sse[k + 2] + sse[k + 1] + sse[k];
        su[k] = arow[k] / denom;
    }
    __syncthreads();

    #pragma unroll
    for (int j = 0; j < 8; ++j) {
        const int k = tid + 256 * j;
        erow[k] = sse[k + 3] * (su[k] + su[k + 1] + su[k + 2] + su[k + 3]);
    }
}

// ---------------------------------------------------------------------------
extern "C" void kernel_launch(void* const* d_in, const int* in_sizes, int n_in,
                              void* d_out, int out_size, void* d_ws, size_t ws_size,
                              hipStream_t stream)
{
    (void)in_sizes; (void)n_in; (void)out_size; (void)ws_size;
    const float* key_enc = (const float*)d_in[0];   // [8,2048,512]
    const float* query   = (const float*)d_in[1];   // [8,256,512]
    const float* noise   = (const float*)d_in[2];   // [8,256,2048]
    const float* Wk_m    = (const float*)d_in[3];
    const float* bk_m    = (const float*)d_in[4];
    const float* Wq_m    = (const float*)d_in[5];
    const float* bq_m    = (const float*)d_in[6];
    const float* rp      = (const float*)d_in[7];
    const float* Wk_c    = (const float*)d_in[8];
    const float* bk_c    = (const float*)d_in[9];
    const float* Wq_c    = (const float*)d_in[10];
    const float* bq_c    = (const float*)d_in[11];
    float* out = (float*)d_out;                     // [8,4,256,2048]

    // workspace layout (floats)
    float* ws = (float*)d_ws;
    float* k_m     = ws;                                   // 8*2048*512
    float* k_c     = k_m + (size_t)BATCH * KLEN * ADIMC;   // 8*2048*512
    float* q_m     = k_c + (size_t)BATCH * KLEN * ADIMC;   // 8*256*512
    float* q_c     = q_m + (size_t)BATCH * QLEN * ADIMC;   // 8*256*512
    float* p_alpha = q_c + (size_t)BATCH * QLEN * ADIMC;   // 8*256*2048 (p, then alpha)
    float* cp      = p_alpha + (size_t)BATCH * QLEN * KLEN;// 8*256*2048

    // 1) projections
    {
        dim3 blk(256);
        dim3 gk(ADIMC / 64, (BATCH * KLEN) / 64);   // (8, 256)
        dim3 gq(ADIMC / 64, (BATCH * QLEN) / 64);   // (8, 32)
        hipLaunchKernelGGL(proj_gemm, gk, blk, 0, stream,
                           key_enc, Wk_m, bk_m, k_m, BATCH * KLEN, KDIM, ADIMC);
        hipLaunchKernelGGL(proj_gemm, gk, blk, 0, stream,
                           key_enc, Wk_c, bk_c, k_c, BATCH * KLEN, KDIM, ADIMC);
        hipLaunchKernelGGL(proj_gemm, gq, blk, 0, stream,
                           query, Wq_m, bq_m, q_m, BATCH * QLEN, KDIM, ADIMC);
        hipLaunchKernelGGL(proj_gemm, gq, blk, 0, stream,
                           query, Wq_c, bq_c, q_c, BATCH * QLEN, KDIM, ADIMC);
    }
    // 2) e_mono -> p_choose
    hipLaunchKernelGGL(pchoose_gemm, dim3(KLEN / 64, QLEN / 64, BATCH), dim3(256), 0, stream,
                       q_m, k_m, noise, rp, p_alpha);
    // 3) cumprod
    hipLaunchKernelGGL(cumprod_kernel, dim3(BATCH * QLEN), dim3(256), 0, stream,
                       p_alpha, cp);
    // 4) alpha recurrence (in-place over p)
    hipLaunchKernelGGL(alpha_kernel, dim3(BATCH), dim3(1024), 0, stream,
                       p_alpha, cp);
    // 5) e_chunk into d_out
    hipLaunchKernelGGL(echunk_gemm, dim3(KLEN / 64, QLEN / 64, BATCH * NHEADS), dim3(256), 0, stream,
                       q_c, k_c, out);
    // 6) beta (overwrites e_chunk rows in d_out)
    hipLaunchKernelGGL(beta_kernel, dim3(BATCH * NHEADS * QLEN), dim3(256), 0, stream,
                       out, p_alpha);
}